// Round 1
// baseline (2148.228 us; speedup 1.0000x reference)
//
#include <hip/hip_runtime.h>

#define H 1024
#define T_STEPS 64
#define S_MEM 512
#define VA 30
#define VW 30000

__device__ __forceinline__ float sigmf(float x) { return 1.f / (1.f + expf(-x)); }

// ---------------- init: gather embeddings, stack slices, zero states ----------------
__global__ __launch_bounds__(256) void k_init(
    const int* __restrict__ actions, const int* __restrict__ words,
    const float* __restrict__ act_emb, const float* __restrict__ word_emb,
    float* __restrict__ X_term, float* __restrict__ X_act,
    float* __restrict__ fin, float* __restrict__ c_term, float* __restrict__ c_act) {
  int b = blockIdx.x, tid = threadIdx.x;
  if (b < T_STEPS) {
    int wi = words[b], ai = actions[b];
    for (int i = tid; i < H; i += 256) {
      float we = word_emb[(size_t)wi * H + i];
      X_term[b * H + i] = we;
      X_act[b * H + i]  = act_emb[(size_t)ai * H + i];
      // stack_h[t+1] = w_e[t]  (states layout: fin[t][2048:3072])
      if (b + 1 < T_STEPS) fin[(size_t)(b + 1) * 4096 + 2048 + i] = we;
    }
    if (b == 0)
      for (int i = tid; i < H; i += 256) fin[2048 + i] = 0.f;  // stack_h[0] = 0
  } else {
    for (int i = tid; i < H; i += 256) {
      c_term[i] = 0.f; c_act[i] = 0.f;
      fin[i] = 0.f; fin[H + i] = 0.f;   // term_h[0] = act_h[0] = 0
    }
  }
}

// ---------------- generic fp32 tiled GEMM: C[64,N] = A[64,K] * op(B) ----------------
// BT=true : B is row-major [N][K]  (C = A * B^T)
// BT=false: B is row-major [K][N]  (C = A * B)
// splitk = gridDim.y; if >1 writes partials P[ks][64][N], else writes Cfinal w/ epilogue.
template<bool BT>
__global__ __launch_bounds__(128) void k_gemm(
    const float* __restrict__ A, int lda,
    const float* __restrict__ B, int ldb,
    int N, int K,
    float* __restrict__ Ppart,
    const float* __restrict__ bias, const float* __restrict__ bias2, int relu,
    float* __restrict__ Cfinal, int ldc) {
  __shared__ __align__(16) float As[32][72];
  __shared__ __align__(16) float Bs[32][72];
  int tid = threadIdx.x;
  int r  = tid & 7;    // rows r*8 .. r*8+7
  int cg = tid >> 3;   // cols cg*4 .. cg*4+3
  int n0 = blockIdx.x * 64;
  int splitk = gridDim.y;
  int klen = K / splitk;
  int kbeg = blockIdx.y * klen;
  float acc[8][4];
#pragma unroll
  for (int i = 0; i < 8; ++i)
#pragma unroll
    for (int j = 0; j < 4; ++j) acc[i][j] = 0.f;

  for (int k0 = kbeg; k0 < kbeg + klen; k0 += 32) {
    for (int e = tid; e < 64 * 32; e += 128) {
      int rr = e >> 5, kk = e & 31;
      As[kk][rr] = A[(size_t)rr * lda + k0 + kk];
    }
    if (BT) {
      for (int e = tid; e < 64 * 32; e += 128) {
        int nn = e >> 5, kk = e & 31;
        int gn = n0 + nn;
        Bs[kk][nn] = (gn < N) ? B[(size_t)gn * ldb + k0 + kk] : 0.f;
      }
    } else {
      for (int e = tid; e < 64 * 32; e += 128) {
        int nn = e & 63, kk = e >> 6;
        int gn = n0 + nn;
        Bs[kk][nn] = (gn < N) ? B[(size_t)(k0 + kk) * ldb + gn] : 0.f;
      }
    }
    __syncthreads();
#pragma unroll 4
    for (int kk = 0; kk < 32; ++kk) {
      float4 a0 = *(const float4*)&As[kk][r * 8];
      float4 a1 = *(const float4*)&As[kk][r * 8 + 4];
      float4 bv = *(const float4*)&Bs[kk][cg * 4];
      float av[8] = {a0.x, a0.y, a0.z, a0.w, a1.x, a1.y, a1.z, a1.w};
      float bb[4] = {bv.x, bv.y, bv.z, bv.w};
#pragma unroll
      for (int i = 0; i < 8; ++i)
#pragma unroll
        for (int j = 0; j < 4; ++j) acc[i][j] += av[i] * bb[j];
    }
    __syncthreads();
  }

  if (splitk > 1) {
    float* P = Ppart + (size_t)blockIdx.y * 64 * N;
#pragma unroll
    for (int i = 0; i < 8; ++i) {
      int row = r * 8 + i;
#pragma unroll
      for (int j = 0; j < 4; ++j) {
        int col = n0 + cg * 4 + j;
        if (col < N) P[(size_t)row * N + col] = acc[i][j];
      }
    }
  } else {
#pragma unroll
    for (int i = 0; i < 8; ++i) {
      int row = r * 8 + i;
#pragma unroll
      for (int j = 0; j < 4; ++j) {
        int col = n0 + cg * 4 + j;
        if (col < N) {
          float v = acc[i][j];
          if (bias)  v += bias[col];
          if (bias2) v += bias2[col];
          if (relu)  v = fmaxf(v, 0.f);
          Cfinal[(size_t)row * ldc + col] = v;
        }
      }
    }
  }
}

// ---------------- split-K reduce + bias (+bias2) (+relu) ----------------
__global__ __launch_bounds__(256) void k_reduce(
    const float* __restrict__ P, int S, int N,
    const float* __restrict__ bias, const float* __restrict__ bias2, int relu,
    float* __restrict__ out, int ldc) {
  int idx = blockIdx.x * 256 + threadIdx.x;
  if (idx >= 64 * N) return;
  int row = idx / N, col = idx - row * N;
  float v = 0.f;
  for (int s = 0; s < S; ++s) v += P[(size_t)s * 64 * N + idx];
  if (bias)  v += bias[col];
  if (bias2) v += bias2[col];
  if (relu)  v = fmaxf(v, 0.f);
  out[(size_t)row * ldc + col] = v;
}

// ---------------- one LSTM recurrence step (both LSTMs), 128 WGs ----------------
// WG w: lstm = w>>6, owns h-elements [k0, k0+16). Reads h from fin[t], writes fin[t+1].
__global__ __launch_bounds__(256) void k_lstm_step(
    const float* __restrict__ Whh_term, const float* __restrict__ Whh_act,
    const float* __restrict__ xg_term, const float* __restrict__ xg_act,
    float* __restrict__ fin, float* __restrict__ c_term, float* __restrict__ c_act,
    int t) {
  __shared__ float hs[1024];
  __shared__ float gs[64];
  int wg = blockIdx.x;
  int lstm = wg >> 6;
  int k0 = (wg & 63) * 16;
  const float* Whh = lstm ? Whh_act : Whh_term;
  const float* xg  = (lstm ? xg_act : xg_term) + (size_t)t * 4096;
  float* cbuf = lstm ? c_act : c_term;
  const float* hin  = fin + (size_t)t * 4096 + lstm * 1024;
  float* hout       = fin + (size_t)(t + 1) * 4096 + lstm * 1024;
  int tid = threadIdx.x;
  for (int i = tid; i < 1024; i += 256) hs[i] = hin[i];
  __syncthreads();
  int d = tid >> 2, p = tid & 3;        // d: which of 64 gate rows; p: K-quarter
  int gate = d >> 4, e = d & 15;
  int row = gate * 1024 + k0 + e;
  const float* wrow = Whh + (size_t)row * 1024 + p * 256;
  const float* hptr = hs + p * 256;
  float sum = 0.f;
#pragma unroll 8
  for (int i = 0; i < 256; i += 4) {
    float4 wv = *(const float4*)(wrow + i);
    float4 hv = *(const float4*)(hptr + i);
    sum += wv.x * hv.x + wv.y * hv.y + wv.z * hv.z + wv.w * hv.w;
  }
  sum += __shfl_xor(sum, 1);
  sum += __shfl_xor(sum, 2);
  if (p == 0) gs[d] = sum + xg[row];
  __syncthreads();
  if (tid < 16) {
    float gi = gs[tid], gf = gs[16 + tid], gg = gs[32 + tid], go = gs[48 + tid];
    float c = cbuf[k0 + tid];
    float c2 = sigmf(gf) * c + sigmf(gi) * tanhf(gg);
    float h2 = sigmf(go) * tanhf(c2);
    cbuf[k0 + tid] = c2;
    hout[k0 + tid] = h2;
  }
}

// ---------------- action logits: [64,30] = ha @ Wa2^T + ba2 ----------------
__global__ __launch_bounds__(256) void k_actlog(
    const float* __restrict__ ha, const float* __restrict__ Wa2,
    const float* __restrict__ ba2, float* __restrict__ out) {
  int t = blockIdx.x, tid = threadIdx.x;
  int v = tid >> 3, p = tid & 7;
  float sum = 0.f;
  if (v < VA) {
    const float* a  = ha + (size_t)t * 1024 + p * 128;
    const float* wr = Wa2 + (size_t)v * 1024 + p * 128;
#pragma unroll 8
    for (int i = 0; i < 128; i += 4) {
      float4 av = *(const float4*)(a + i);
      float4 wv = *(const float4*)(wr + i);
      sum += av.x * wv.x + av.y * wv.y + av.z * wv.z + av.w * wv.w;
    }
  }
  sum += __shfl_xor(sum, 1);
  sum += __shfl_xor(sum, 2);
  sum += __shfl_xor(sum, 4);
  if (p == 0 && v < VA) out[(size_t)t * VA + v] = sum + ba2[v];
}

extern "C" void kernel_launch(void* const* d_in, const int* in_sizes, int n_in,
                              void* d_out, int out_size, void* d_ws, size_t ws_size,
                              hipStream_t stream) {
  const float* memory   = (const float*)d_in[0];
  const int*   actions  = (const int*)d_in[1];
  const int*   words    = (const int*)d_in[2];
  const float* term_Wih = (const float*)d_in[3];
  const float* term_Whh = (const float*)d_in[4];
  const float* term_bih = (const float*)d_in[5];
  const float* term_bhh = (const float*)d_in[6];
  const float* act_Wih  = (const float*)d_in[7];
  const float* act_Whh  = (const float*)d_in[8];
  const float* act_bih  = (const float*)d_in[9];
  const float* act_bhh  = (const float*)d_in[10];
  const float* Wq  = (const float*)d_in[11];
  const float* bq  = (const float*)d_in[12];
  const float* Wa1 = (const float*)d_in[13];
  const float* ba1 = (const float*)d_in[14];
  const float* Wa2 = (const float*)d_in[15];
  const float* ba2 = (const float*)d_in[16];
  const float* Ww1 = (const float*)d_in[17];
  const float* bw1 = (const float*)d_in[18];
  const float* Ww2 = (const float*)d_in[19];
  const float* bw2 = (const float*)d_in[20];
  const float* act_emb  = (const float*)d_in[21];
  const float* word_emb = (const float*)d_in[22];
  float* out = (float*)d_out;

  // workspace layout (floats)
  float* w       = (float*)d_ws;
  float* X_term  = w;                   // 64*1024
  float* X_act   = X_term + 65536;      // 64*1024
  float* xg_term = X_act + 65536;       // 64*4096
  float* xg_act  = xg_term + 262144;    // 64*4096
  float* c_term  = xg_act + 262144;     // 1024
  float* c_act   = c_term + 1024;       // 1024
  float* fin     = c_act + 1024;        // 64*4096  [term_h | act_h | stack | ctx]
  float* qbuf    = fin + 262144;        // 64*1024
  float* attn    = qbuf + 65536;        // 64*512
  float* ha      = attn + 32768;        // 64*1024
  float* hw      = ha + 65536;          // 64*1024
  float* P       = hw + 65536;          // up to 8*64*1024 / 2*64*4096 = 524288

  k_init<<<65, 256, 0, stream>>>(actions, words, act_emb, word_emb,
                                 X_term, X_act, fin, c_term, c_act);

  // input-side gate pre-GEMMs: xg = X @ Wih^T + bih + bhh
  k_gemm<true><<<dim3(64, 2), 128, 0, stream>>>(X_term, 1024, term_Wih, 1024, 4096, 1024,
                                                P, nullptr, nullptr, 0, nullptr, 0);
  k_reduce<<<(64 * 4096) / 256, 256, 0, stream>>>(P, 2, 4096, term_bih, term_bhh, 0, xg_term, 4096);
  k_gemm<true><<<dim3(64, 2), 128, 0, stream>>>(X_act, 1024, act_Wih, 1024, 4096, 1024,
                                                P, nullptr, nullptr, 0, nullptr, 0);
  k_reduce<<<(64 * 4096) / 256, 256, 0, stream>>>(P, 2, 4096, act_bih, act_bhh, 0, xg_act, 4096);

  // sequential recurrence: h[t] -> h[t+1]  (t = 0..62; step 63's update is unused)
  for (int t = 0; t < 63; ++t)
    k_lstm_step<<<128, 256, 0, stream>>>(term_Whh, act_Whh, xg_term, xg_act,
                                         fin, c_term, c_act, t);

  // q = states @ Wq^T + bq           (states = fin[:, 0:3072])
  k_gemm<true><<<dim3(16, 4), 128, 0, stream>>>(fin, 4096, Wq, 3072, 1024, 3072,
                                                P, nullptr, nullptr, 0, nullptr, 0);
  k_reduce<<<(64 * 1024) / 256, 256, 0, stream>>>(P, 4, 1024, bq, nullptr, 0, qbuf, 1024);

  // attn[t,s] = q[t] . memory[s]     (no softmax in reference)
  k_gemm<true><<<dim3(8, 8), 128, 0, stream>>>(qbuf, 1024, memory, 1024, 512, 1024,
                                               P, nullptr, nullptr, 0, nullptr, 0);
  k_reduce<<<(64 * 512) / 256, 256, 0, stream>>>(P, 8, 512, nullptr, nullptr, 0, attn, 512);

  // ctx[t,d] = sum_s attn[t,s] * memory[s,d]  -> fin[:, 3072:4096]
  k_gemm<false><<<dim3(16, 4), 128, 0, stream>>>(attn, 512, memory, 1024, 1024, 512,
                                                 P, nullptr, nullptr, 0, nullptr, 0);
  k_reduce<<<(64 * 1024) / 256, 256, 0, stream>>>(P, 4, 1024, nullptr, nullptr, 0, fin + 3072, 4096);

  // ha = relu(final @ Wa1^T + ba1), hw = relu(final @ Ww1^T + bw1)
  k_gemm<true><<<dim3(16, 4), 128, 0, stream>>>(fin, 4096, Wa1, 4096, 1024, 4096,
                                                P, nullptr, nullptr, 0, nullptr, 0);
  k_reduce<<<(64 * 1024) / 256, 256, 0, stream>>>(P, 4, 1024, ba1, nullptr, 1, ha, 1024);
  k_gemm<true><<<dim3(16, 4), 128, 0, stream>>>(fin, 4096, Ww1, 4096, 1024, 4096,
                                                P, nullptr, nullptr, 0, nullptr, 0);
  k_reduce<<<(64 * 1024) / 256, 256, 0, stream>>>(P, 4, 1024, bw1, nullptr, 1, hw, 1024);

  // act_logits -> out[0:1920]
  k_actlog<<<64, 256, 0, stream>>>(ha, Wa2, ba2, out);

  // word_logits = hw @ Ww2^T + bw2 -> out[1920:]
  k_gemm<true><<<dim3(469, 1), 128, 0, stream>>>(hw, 1024, Ww2, 1024, VW, 1024,
                                                 nullptr, bw2, nullptr, 0, out + 1920, VW);
}